// Round 1
// baseline (145.203 us; speedup 1.0000x reference)
//
#include <hip/hip_runtime.h>

// PCEN over x[B=64, M=128, T=4000] fp32, T contiguous.
// m_t = (1-S) m_{t-1} + S x_t ;  pcen = sqrt(x/(eps+m)^0.98 + 2) - sqrt(2)
// Parallelized over (row, chunk): each chunk of L=500 timesteps recomputes its
// incoming EMA state by a 500-step warmup over the previous chunk's samples
// (0.975^500 ~ 3e-6 -> output error ~1e-5, far below threshold).

#define TT      4000
#define CHUNK_L 500
#define NCHUNKS 8
#define NROWS   8192   // 64 * 128

__global__ __launch_bounds__(256) void pcen_kernel(const float* __restrict__ x,
                                                   float* __restrict__ out) {
    const int g = blockIdx.x * blockDim.x + threadIdx.x;
    const int chunk = g & (NCHUNKS - 1);
    const int row   = g >> 3;
    if (row >= NROWS) return;

    const float S      = 0.025f;
    const float A      = 0.975f;           // 1 - S
    const float EPS    = 1e-6f;
    const float NALPHA = -0.98f;
    const float DELTA  = 2.0f;
    const float DELTA_R = 1.41421356237f;  // 2^0.5

    const float* xr = x   + (long)row * TT;
    float*       orw = out + (long)row * TT;
    const int t0 = chunk * CHUNK_L;

    float m = 0.0f;

    // Warmup: rebuild EMA state from the previous chunk's 500 samples (m=0 start).
    if (chunk != 0) {
        const float4* w = (const float4*)(xr + t0 - CHUNK_L);
        #pragma unroll 4
        for (int i = 0; i < CHUNK_L / 4; ++i) {
            float4 v = w[i];
            m = fmaf(A, m, S * v.x);
            m = fmaf(A, m, S * v.y);
            m = fmaf(A, m, S * v.z);
            m = fmaf(A, m, S * v.w);
        }
    }

    // Main: EMA + PCEN nonlinearity, float4 in / float4 out.
    const float4* xi = (const float4*)(xr + t0);
    float4*       oi = (float4*)(orw + t0);
    #pragma unroll 4
    for (int i = 0; i < CHUNK_L / 4; ++i) {
        float4 v = xi[i];
        float4 o;

        m   = fmaf(A, m, S * v.x);
        o.x = sqrtf(fmaf(v.x, exp2f(NALPHA * log2f(m + EPS)), DELTA)) - DELTA_R;

        m   = fmaf(A, m, S * v.y);
        o.y = sqrtf(fmaf(v.y, exp2f(NALPHA * log2f(m + EPS)), DELTA)) - DELTA_R;

        m   = fmaf(A, m, S * v.z);
        o.z = sqrtf(fmaf(v.z, exp2f(NALPHA * log2f(m + EPS)), DELTA)) - DELTA_R;

        m   = fmaf(A, m, S * v.w);
        o.w = sqrtf(fmaf(v.w, exp2f(NALPHA * log2f(m + EPS)), DELTA)) - DELTA_R;

        oi[i] = o;
    }
}

extern "C" void kernel_launch(void* const* d_in, const int* in_sizes, int n_in,
                              void* d_out, int out_size, void* d_ws, size_t ws_size,
                              hipStream_t stream) {
    const float* x = (const float*)d_in[0];
    float* out = (float*)d_out;
    const int total_threads = NROWS * NCHUNKS;  // 65536
    const int block = 256;
    const int grid = total_threads / block;     // 256
    pcen_kernel<<<grid, block, 0, stream>>>(x, out);
}

// Round 2
// 80.768 us; speedup vs baseline: 1.7978x; 1.7978x over previous
//
#include <hip/hip_runtime.h>

// PCEN over x[B=64, M=128, T=4000] fp32, T contiguous.
// m_t = (1-S) m_{t-1} + S x_t ;  pcen = sqrt(x/(eps+m)^0.98 + 2) - sqrt(2)
// Chunked-scan: each thread owns one (row, chunk). Chunks are 256 timesteps
// (last = 160), 1024B-aligned. Incoming EMA state is rebuilt by a 256-step
// warmup over the previous chunk (0.975^256 ~ 1.5e-3 -> output err ~1.5e-3,
// threshold is 9.7e-2). 16 chunks/row -> 131072 threads = 8 waves/CU.

#define TT      4000
#define CL      256
#define NCH     16
#define NROWS   8192   // 64 * 128

__global__ __launch_bounds__(256) void pcen_kernel(const float* __restrict__ x,
                                                   float* __restrict__ out) {
    const int g     = blockIdx.x * blockDim.x + threadIdx.x;
    const int chunk = g & (NCH - 1);
    const int row   = g >> 4;

    const float S       = 0.025f;
    const float A       = 0.975f;           // 1 - S
    const float EPS     = 1e-6f;
    const float NALPHA  = -0.98f;
    const float DELTA   = 2.0f;
    const float DELTA_R = 1.41421356237f;   // 2^0.5

    const float* xr  = x   + (long)row * TT;
    float*       orw = out + (long)row * TT;
    const int t0  = chunk * CL;
    const int len = (chunk == NCH - 1) ? (TT - t0) : CL;   // 160 for last chunk

    float m = 0.0f;

    // Warmup: rebuild EMA state from the previous 256 samples (m=0 start).
    if (chunk != 0) {
        const float4* w = (const float4*)(xr + t0 - CL);
        #pragma unroll 8
        for (int i = 0; i < CL / 4; ++i) {
            float4 v = w[i];
            m = fmaf(A, m, S * v.x);
            m = fmaf(A, m, S * v.y);
            m = fmaf(A, m, S * v.z);
            m = fmaf(A, m, S * v.w);
        }
    }

    // Main: EMA + PCEN nonlinearity, float4 in / float4 out.
    const float4* xi = (const float4*)(xr + t0);
    float4*       oi = (float4*)(orw + t0);
    const int n4 = len >> 2;
    #pragma unroll 8
    for (int i = 0; i < n4; ++i) {
        float4 v = xi[i];
        float4 o;

        m   = fmaf(A, m, S * v.x);
        o.x = sqrtf(fmaf(v.x, exp2f(NALPHA * log2f(m + EPS)), DELTA)) - DELTA_R;

        m   = fmaf(A, m, S * v.y);
        o.y = sqrtf(fmaf(v.y, exp2f(NALPHA * log2f(m + EPS)), DELTA)) - DELTA_R;

        m   = fmaf(A, m, S * v.z);
        o.z = sqrtf(fmaf(v.z, exp2f(NALPHA * log2f(m + EPS)), DELTA)) - DELTA_R;

        m   = fmaf(A, m, S * v.w);
        o.w = sqrtf(fmaf(v.w, exp2f(NALPHA * log2f(m + EPS)), DELTA)) - DELTA_R;

        oi[i] = o;
    }
}

extern "C" void kernel_launch(void* const* d_in, const int* in_sizes, int n_in,
                              void* d_out, int out_size, void* d_ws, size_t ws_size,
                              hipStream_t stream) {
    const float* x = (const float*)d_in[0];
    float* out = (float*)d_out;
    const int total_threads = NROWS * NCH;   // 131072
    const int block = 256;
    const int grid = total_threads / block;  // 512
    pcen_kernel<<<grid, block, 0, stream>>>(x, out);
}

// Round 3
// 48.605 us; speedup vs baseline: 2.9874x; 1.6617x over previous
//
#include <hip/hip_runtime.h>

// PCEN over x[B=64, M=128, T=4000] fp32, T contiguous.
// m_t = A*m_{t-1} + S*x_t (A=0.975) ; pcen = sqrt(x/(eps+m)^0.98 + 2) - sqrt(2)
//
// One wave (64 lanes) per row. Per iteration the wave processes 256 contiguous
// timesteps: lane l loads float4 at [it*256 + 4l] (1KB contiguous per wave ->
// fully coalesced loads AND stores). EMA is a linear recurrence = associative
// scan: 4-step lane-local scan, then 6-step shfl_up Hillis-Steele scan with
// compile-time decay factors A^4..A^128, then per-element recompute from the
// previous lane's total. Cross-iteration carry = 1 fma + broadcast. Exact
// algorithm (no chunk approximation).

#define TT     4000
#define NROWS  8192   // 64*128
#define NFULL  15     // 15*256 = 3840 full-wave batches
#define TAILL  40     // tail: 160 elems = 40 lanes * 4

__global__ __launch_bounds__(256, 8) void pcen_kernel(const float* __restrict__ x,
                                                      float* __restrict__ out) {
    const int wid  = (blockIdx.x * blockDim.x + threadIdx.x) >> 6;  // = row
    const int lane = threadIdx.x & 63;

    const float S = 0.025f, A = 0.975f, EPS = 1e-6f, NA = -0.98f;
    const float SQRT2 = 1.41421356237f;

    // Compile-time-foldable decay powers.
    const float A4   = A * A * A * A;
    const float A8   = A4 * A4;
    const float A16  = A8 * A8;
    const float A32  = A16 * A16;
    const float A64  = A32 * A32;
    const float A128 = A64 * A64;
    const float A256 = A128 * A128;

    // powAl = A^(4*lane), built from lane bits (once).
    float powAl = 1.0f;
    if (lane & 1)  powAl *= A4;
    if (lane & 2)  powAl *= A8;
    if (lane & 4)  powAl *= A16;
    if (lane & 8)  powAl *= A32;
    if (lane & 16) powAl *= A64;
    if (lane & 32) powAl *= A128;

    const float4* xi = (const float4*)(x   + (long)wid * TT) + lane;
    float4*       oi = (float4*)      (out + (long)wid * TT) + lane;

    float carry = 0.0f;  // EMA state entering this batch (uniform across wave)

    #pragma unroll 2
    for (int it = 0; it <= NFULL; ++it) {
        const bool active = (it < NFULL) | (lane < TAILL);
        float4 v = make_float4(0.0f, 0.0f, 0.0f, 0.0f);
        if (active) v = xi[it * 64];

        // Lane-local 4-step EMA from 0.
        float b = S * v.x;
        b = fmaf(A, b, S * v.y);
        b = fmaf(A, b, S * v.z);
        float B = fmaf(A, b, S * v.w);   // lane aggregate (from state 0)

        // Wave inclusive scan; per-lane segment decay is uniform A^4.
        float t;
        t = __shfl_up(B, 1, 64);  B = fmaf(A4,   (lane >= 1)  ? t : 0.0f, B);
        t = __shfl_up(B, 2, 64);  B = fmaf(A8,   (lane >= 2)  ? t : 0.0f, B);
        t = __shfl_up(B, 4, 64);  B = fmaf(A16,  (lane >= 4)  ? t : 0.0f, B);
        t = __shfl_up(B, 8, 64);  B = fmaf(A32,  (lane >= 8)  ? t : 0.0f, B);
        t = __shfl_up(B, 16, 64); B = fmaf(A64,  (lane >= 16) ? t : 0.0f, B);
        t = __shfl_up(B, 32, 64); B = fmaf(A128, (lane >= 32) ? t : 0.0f, B);

        // State entering this lane = prev lane's scan total + decayed carry.
        float bp = __shfl_up(B, 1, 64);
        float mprev = fmaf(powAl, carry, (lane >= 1) ? bp : 0.0f);

        // Carry for next batch (serial chain: 1 broadcast + 1 fma per iter).
        float b63 = __shfl(B, 63, 64);
        carry = fmaf(A256, carry, b63);

        // Recompute per-element states + PCEN nonlinearity.
        float m = mprev;
        float4 o;
        m = fmaf(A, m, S * v.x);
        o.x = sqrtf(fmaf(v.x, exp2f(NA * log2f(m + EPS)), 2.0f)) - SQRT2;
        m = fmaf(A, m, S * v.y);
        o.y = sqrtf(fmaf(v.y, exp2f(NA * log2f(m + EPS)), 2.0f)) - SQRT2;
        m = fmaf(A, m, S * v.z);
        o.z = sqrtf(fmaf(v.z, exp2f(NA * log2f(m + EPS)), 2.0f)) - SQRT2;
        m = fmaf(A, m, S * v.w);
        o.w = sqrtf(fmaf(v.w, exp2f(NA * log2f(m + EPS)), 2.0f)) - SQRT2;

        if (active) oi[it * 64] = o;
    }
}

extern "C" void kernel_launch(void* const* d_in, const int* in_sizes, int n_in,
                              void* d_out, int out_size, void* d_ws, size_t ws_size,
                              hipStream_t stream) {
    const float* x = (const float*)d_in[0];
    float* out = (float*)d_out;
    // One wave per row: 8192 waves = 524288 threads, 256/block -> 2048 blocks.
    const int block = 256;
    const int grid = (NROWS * 64) / block;
    pcen_kernel<<<grid, block, 0, stream>>>(x, out);
}